// Round 2
// baseline (1023.198 us; speedup 1.0000x reference)
//
#include <hip/hip_runtime.h>
#include <hip/hip_bf16.h>
#include <cstdint>
#include <cstddef>

#define NN 100000
#define NE 1600000
#define DIM 128
#define KIN 117
#define NLAYERS 3
#define NB 98           // ceil(NN/1024)

// ---------------- CSR build ----------------

__global__ void k_hist(const int* __restrict__ dst, int* __restrict__ cnt) {
  int i = blockIdx.x * blockDim.x + threadIdx.x;
  if (i < NE) atomicAdd(&cnt[dst[i]], 1);
}

__global__ void k_scanA(const int* __restrict__ cnt, int* __restrict__ part,
                        int* __restrict__ bsum) {
  __shared__ int sh[1024];
  int tid = threadIdx.x;
  int i = blockIdx.x * 1024 + tid;
  int v = (i < NN) ? cnt[i] : 0;
  sh[tid] = v;
  __syncthreads();
  for (int off = 1; off < 1024; off <<= 1) {
    int t = (tid >= off) ? sh[tid - off] : 0;
    __syncthreads();
    sh[tid] += t;
    __syncthreads();
  }
  if (i < NN) part[i] = sh[tid] - v;   // exclusive within block
  if (tid == 1023) bsum[blockIdx.x] = sh[1023];
}

__global__ void k_scanB(const int* __restrict__ bsum, int* __restrict__ boff,
                        int* __restrict__ rptr) {
  if (threadIdx.x == 0 && blockIdx.x == 0) {
    int run = 0;
    for (int b = 0; b < NB; ++b) { boff[b] = run; run += bsum[b]; }
    rptr[NN] = run;  // == NE
  }
}

__global__ void k_scanC(const int* __restrict__ part, const int* __restrict__ boff,
                        int* __restrict__ rptr, int* __restrict__ cursor) {
  int i = blockIdx.x * 1024 + threadIdx.x;
  if (i < NN) {
    int v = part[i] + boff[i >> 10];
    rptr[i] = v;
    cursor[i] = v;
  }
}

__global__ void k_scatter(const int* __restrict__ src, const int* __restrict__ dst,
                          int* __restrict__ cursor, int* __restrict__ ssrc) {
  int i = blockIdx.x * blockDim.x + threadIdx.x;
  if (i < NE) {
    int p = atomicAdd(&cursor[dst[i]], 1);
    ssrc[p] = src[i];
  }
}

// ---------------- mean aggregation: one wave per node ----------------
// Wave-uniform node/beg/end/index scalarized via readfirstlane; 4-deep
// unroll gives 4 independent index->row load chains in flight.

__global__ __launch_bounds__(256) void k_agg(const float* __restrict__ x,
                                             const int* __restrict__ rptr,
                                             const int* __restrict__ ssrc,
                                             float* __restrict__ mean) {
  int gid = blockIdx.x * blockDim.x + threadIdx.x;
  int node = __builtin_amdgcn_readfirstlane(gid >> 6);
  int lane = threadIdx.x & 63;
  if (node >= NN) return;
  int beg = __builtin_amdgcn_readfirstlane(rptr[node]);
  int end = __builtin_amdgcn_readfirstlane(rptr[node + 1]);
  int c0 = lane * 2;
  float ax = 0.f, ay = 0.f;
  int e = beg;
  for (; e + 3 < end; e += 4) {
    int s0 = __builtin_amdgcn_readfirstlane(ssrc[e]);
    int s1 = __builtin_amdgcn_readfirstlane(ssrc[e + 1]);
    int s2 = __builtin_amdgcn_readfirstlane(ssrc[e + 2]);
    int s3 = __builtin_amdgcn_readfirstlane(ssrc[e + 3]);
    float2 v0 = *reinterpret_cast<const float2*>(x + (size_t)s0 * DIM + c0);
    float2 v1 = *reinterpret_cast<const float2*>(x + (size_t)s1 * DIM + c0);
    float2 v2 = *reinterpret_cast<const float2*>(x + (size_t)s2 * DIM + c0);
    float2 v3 = *reinterpret_cast<const float2*>(x + (size_t)s3 * DIM + c0);
    ax += (v0.x + v1.x) + (v2.x + v3.x);
    ay += (v0.y + v1.y) + (v2.y + v3.y);
  }
  for (; e < end; ++e) {
    int s0 = __builtin_amdgcn_readfirstlane(ssrc[e]);
    float2 v0 = *reinterpret_cast<const float2*>(x + (size_t)s0 * DIM + c0);
    ax += v0.x;
    ay += v0.y;
  }
  int deg = end - beg;
  float inv = 1.0f / (float)(deg > 0 ? deg : 1);
  *reinterpret_cast<float2*>(mean + (size_t)node * DIM + c0) =
      make_float2(ax * inv, ay * inv);
}

// ---------------- fused GEMM: out = act(A@W [+ A2@W2] + bias) ----------------
// Block: 256 threads, 128 rows x 128 cols, BK=32. Micro: 8x8 per thread.
// ACT: 0 = tanh, 1 = relu.

template <int ACT, bool TWO>
__global__ __launch_bounds__(256) void k_gemm(
    const float* __restrict__ A, int lda, int K,
    const float* __restrict__ W,               // [K][128] row-major
    const float* __restrict__ A2,              // [M][128] or null
    const float* __restrict__ W2,              // [128][128] or null
    const float* __restrict__ bias,            // [128]
    float* __restrict__ out, int M) {
  __shared__ float Xs[32][130];  // transposed: Xs[k][row]
  __shared__ float Ws[32][140];  // Ws[k][col]
  const int tid = threadIdx.x;
  const int trow = tid >> 4;   // 0..15 -> rows trow*8 .. +7
  const int tcol = tid & 15;   // cols tcol*4..+3 and 64+tcol*4..+3
  const int m0 = blockIdx.x * 128;

  float acc[8][8];
#pragma unroll
  for (int i = 0; i < 8; ++i)
#pragma unroll
    for (int j = 0; j < 8; ++j) acc[i][j] = 0.f;

  const int npass = TWO ? 2 : 1;
  for (int pass = 0; pass < npass; ++pass) {
    const float* Ap = pass ? A2 : A;
    const float* Wp = pass ? W2 : W;
    const int ld = pass ? DIM : lda;
    const int Kp = pass ? DIM : K;
    for (int kt = 0; kt < Kp; kt += 32) {
      // ---- stage A tile (transposed into LDS) ----
      {
        int r = tid >> 1;        // 0..127
        int h = tid & 1;         // 0/1 -> 16 floats each
        int row = m0 + r;
        int kbase = kt + h * 16;
        const float* srcp = Ap + (size_t)row * ld + kbase;
        if (row < M && (ld & 3) == 0 && kbase + 15 < Kp) {
#pragma unroll
          for (int j4 = 0; j4 < 4; ++j4) {
            float4 v = *reinterpret_cast<const float4*>(srcp + j4 * 4);
            Xs[h * 16 + j4 * 4 + 0][r] = v.x;
            Xs[h * 16 + j4 * 4 + 1][r] = v.y;
            Xs[h * 16 + j4 * 4 + 2][r] = v.z;
            Xs[h * 16 + j4 * 4 + 3][r] = v.w;
          }
        } else {
#pragma unroll
          for (int j = 0; j < 16; ++j) {
            int k = kbase + j;
            float v = 0.f;
            if (row < M && k < Kp) v = srcp[j];
            Xs[h * 16 + j][r] = v;
          }
        }
      }
      // ---- stage W tile ----
      {
        int kk = tid >> 3;       // 0..31
        int seg = tid & 7;       // 16 floats each
        int k = kt + kk;
        if (k < Kp) {
          const float* wsrc = Wp + (size_t)k * DIM + seg * 16;
#pragma unroll
          for (int j4 = 0; j4 < 4; ++j4) {
            float4 v = *reinterpret_cast<const float4*>(wsrc + j4 * 4);
            *reinterpret_cast<float4*>(&Ws[kk][seg * 16 + j4 * 4]) = v;
          }
        } else {
#pragma unroll
          for (int j = 0; j < 16; ++j) Ws[kk][seg * 16 + j] = 0.f;
        }
      }
      __syncthreads();
      // ---- inner product ----
#pragma unroll
      for (int k = 0; k < 32; ++k) {
        float2 t0 = *reinterpret_cast<const float2*>(&Xs[k][trow * 8 + 0]);
        float2 t1 = *reinterpret_cast<const float2*>(&Xs[k][trow * 8 + 2]);
        float2 t2 = *reinterpret_cast<const float2*>(&Xs[k][trow * 8 + 4]);
        float2 t3 = *reinterpret_cast<const float2*>(&Xs[k][trow * 8 + 6]);
        float4 b0 = *reinterpret_cast<const float4*>(&Ws[k][tcol * 4]);
        float4 b1 = *reinterpret_cast<const float4*>(&Ws[k][64 + tcol * 4]);
        float a[8] = {t0.x, t0.y, t1.x, t1.y, t2.x, t2.y, t3.x, t3.y};
        float b[8] = {b0.x, b0.y, b0.z, b0.w, b1.x, b1.y, b1.z, b1.w};
#pragma unroll
        for (int i = 0; i < 8; ++i)
#pragma unroll
          for (int j = 0; j < 8; ++j) acc[i][j] = fmaf(a[i], b[j], acc[i][j]);
      }
      __syncthreads();
    }
  }

  // ---- epilogue ----
  float4 bb0 = *reinterpret_cast<const float4*>(bias + tcol * 4);
  float4 bb1 = *reinterpret_cast<const float4*>(bias + 64 + tcol * 4);
  float bv[8] = {bb0.x, bb0.y, bb0.z, bb0.w, bb1.x, bb1.y, bb1.z, bb1.w};
#pragma unroll
  for (int i = 0; i < 8; ++i) {
    int row = m0 + trow * 8 + i;
    if (row < M) {
      float v[8];
#pragma unroll
      for (int j = 0; j < 8; ++j) {
        float t = acc[i][j] + bv[j];
        if (ACT == 0) {
          t = tanhf(t);
        } else {
          t = fmaxf(t, 0.f);
        }
        v[j] = t;
      }
      *reinterpret_cast<float4*>(out + (size_t)row * DIM + tcol * 4) =
          make_float4(v[0], v[1], v[2], v[3]);
      *reinterpret_cast<float4*>(out + (size_t)row * DIM + 64 + tcol * 4) =
          make_float4(v[4], v[5], v[6], v[7]);
    }
  }
}

// ---------------- launcher ----------------

extern "C" void kernel_launch(void* const* d_in, const int* in_sizes, int n_in,
                              void* d_out, int out_size, void* d_ws, size_t ws_size,
                              hipStream_t stream) {
  const float* h0 = (const float*)d_in[0];
  const int* srcp = (const int*)d_in[1];
  const int* dstp = (const int*)d_in[2];
  const float* W_in = (const float*)d_in[3];
  const float* b_in = (const float*)d_in[4];
  const float* W_self = (const float*)d_in[5];
  const float* W_neigh = (const float*)d_in[6];
  const float* b_sage = (const float*)d_in[7];
  float* outf = (float*)d_out;

  // workspace carve-up (~111 MB)
  char* p = (char*)d_ws;
  auto alloc = [&](size_t bytes) {
    char* r = p;
    p += (bytes + 255) & ~(size_t)255;
    return r;
  };
  float* mean = (float*)alloc((size_t)NN * DIM * 4);
  float* hA = (float*)alloc((size_t)NN * DIM * 4);
  int* cnt = (int*)alloc((size_t)NN * 4);
  int* part = (int*)alloc((size_t)NN * 4);
  int* rptr = (int*)alloc((size_t)(NN + 1) * 4);
  int* cursor = (int*)alloc((size_t)NN * 4);
  int* ssrcS = (int*)alloc((size_t)NE * 4);
  int* bsum = (int*)alloc((size_t)NB * 4);
  int* boff = (int*)alloc((size_t)NB * 4);

  // ---- CSR build (once per call, reused by all 3 layers) ----
  hipMemsetAsync(cnt, 0, (size_t)NN * 4, stream);
  k_hist<<<(NE + 255) / 256, 256, 0, stream>>>(dstp, cnt);
  k_scanA<<<NB, 1024, 0, stream>>>(cnt, part, bsum);
  k_scanB<<<1, 64, 0, stream>>>(bsum, boff, rptr);
  k_scanC<<<NB, 1024, 0, stream>>>(part, boff, rptr, cursor);
  k_scatter<<<(NE + 255) / 256, 256, 0, stream>>>(srcp, dstp, cursor, ssrcS);

  const int GB = (NN + 127) / 128;  // 782 blocks

  // ---- f_in: hA = tanh(h0 @ W_in + b_in) ----
  k_gemm<0, false><<<GB, 256, 0, stream>>>(h0, KIN, KIN, W_in, nullptr, nullptr,
                                           b_in, hA, NN);

  // ---- 3 SAGE layers, ping-pong hA <-> d_out ----
  for (int l = 0; l < NLAYERS; ++l) {
    const float* x = (l == 1) ? outf : hA;
    float* o = (l == 1) ? hA : outf;
    const float* Wse = W_self + (size_t)l * DIM * DIM;
    const float* Wne = W_neigh + (size_t)l * DIM * DIM;
    const float* bs = b_sage + (size_t)l * DIM;
    k_agg<<<(NN * 64 + 255) / 256, 256, 0, stream>>>(x, rptr, ssrcS, mean);
    k_gemm<1, true><<<GB, 256, 0, stream>>>(x, DIM, DIM, Wse, mean, Wne, bs, o, NN);
  }
}

// Round 10
// 845.228 us; speedup vs baseline: 1.2106x; 1.2106x over previous
//
#include <hip/hip_runtime.h>
#include <hip/hip_bf16.h>
#include <cstdint>
#include <cstddef>

#define NN 100000
#define NE 1600000
#define DIM 128
#define KIN 117
#define NLAYERS 3
#define NB 98           // ceil(NN/1024)
#define NMAT 7          // W_in + 3x W_self + 3x W_neigh

typedef __attribute__((ext_vector_type(8))) short s16x8;
typedef __attribute__((ext_vector_type(8))) __bf16 bf16x8;
typedef __attribute__((ext_vector_type(4))) float f32x4;

// float -> bf16 bits, round-to-nearest-even (values are finite)
__device__ __forceinline__ unsigned short f2bf(float f) {
  unsigned int u = __float_as_uint(f);
  unsigned int r = (u + 0x7fffu + ((u >> 16) & 1u)) >> 16;
  return (unsigned short)r;
}
__device__ __forceinline__ float bf2f(unsigned short b) {
  return __uint_as_float(((unsigned int)b) << 16);
}

// ---------------- CSR build ----------------

__global__ void k_hist(const int* __restrict__ dst, int* __restrict__ cnt) {
  int i = blockIdx.x * blockDim.x + threadIdx.x;
  if (i < NE) atomicAdd(&cnt[dst[i]], 1);
}

__global__ void k_scanA(const int* __restrict__ cnt, int* __restrict__ part,
                        int* __restrict__ bsum) {
  __shared__ int sh[1024];
  int tid = threadIdx.x;
  int i = blockIdx.x * 1024 + tid;
  int v = (i < NN) ? cnt[i] : 0;
  sh[tid] = v;
  __syncthreads();
  for (int off = 1; off < 1024; off <<= 1) {
    int t = (tid >= off) ? sh[tid - off] : 0;
    __syncthreads();
    sh[tid] += t;
    __syncthreads();
  }
  if (i < NN) part[i] = sh[tid] - v;   // exclusive within block
  if (tid == 1023) bsum[blockIdx.x] = sh[1023];
}

__global__ void k_scanB(const int* __restrict__ bsum, int* __restrict__ boff,
                        int* __restrict__ rptr) {
  if (threadIdx.x == 0 && blockIdx.x == 0) {
    int run = 0;
    for (int b = 0; b < NB; ++b) { boff[b] = run; run += bsum[b]; }
    rptr[NN] = run;  // == NE
  }
}

__global__ void k_scanC(const int* __restrict__ part, const int* __restrict__ boff,
                        int* __restrict__ rptr, int* __restrict__ cursor) {
  int i = blockIdx.x * 1024 + threadIdx.x;
  if (i < NN) {
    int v = part[i] + boff[i >> 10];
    rptr[i] = v;
    cursor[i] = v;
  }
}

__global__ void k_scatter(const int* __restrict__ src, const int* __restrict__ dst,
                          int* __restrict__ cursor, int* __restrict__ ssrc) {
  int i = blockIdx.x * blockDim.x + threadIdx.x;
  if (i < NE) {
    int p = atomicAdd(&cursor[dst[i]], 1);
    ssrc[p] = src[i];
  }
}

// ---------------- mean aggregation: one wave per node ----------------

__global__ __launch_bounds__(256) void k_agg(const float* __restrict__ x,
                                             const int* __restrict__ rptr,
                                             const int* __restrict__ ssrc,
                                             float* __restrict__ mean) {
  int gid = blockIdx.x * blockDim.x + threadIdx.x;
  int node = __builtin_amdgcn_readfirstlane(gid >> 6);
  int lane = threadIdx.x & 63;
  if (node >= NN) return;
  int beg = __builtin_amdgcn_readfirstlane(rptr[node]);
  int end = __builtin_amdgcn_readfirstlane(rptr[node + 1]);
  int c0 = lane * 2;
  float ax = 0.f, ay = 0.f;
  int e = beg;
  for (; e + 3 < end; e += 4) {
    int s0 = __builtin_amdgcn_readfirstlane(ssrc[e]);
    int s1 = __builtin_amdgcn_readfirstlane(ssrc[e + 1]);
    int s2 = __builtin_amdgcn_readfirstlane(ssrc[e + 2]);
    int s3 = __builtin_amdgcn_readfirstlane(ssrc[e + 3]);
    float2 v0 = *reinterpret_cast<const float2*>(x + (size_t)s0 * DIM + c0);
    float2 v1 = *reinterpret_cast<const float2*>(x + (size_t)s1 * DIM + c0);
    float2 v2 = *reinterpret_cast<const float2*>(x + (size_t)s2 * DIM + c0);
    float2 v3 = *reinterpret_cast<const float2*>(x + (size_t)s3 * DIM + c0);
    ax += (v0.x + v1.x) + (v2.x + v3.x);
    ay += (v0.y + v1.y) + (v2.y + v3.y);
  }
  for (; e < end; ++e) {
    int s0 = __builtin_amdgcn_readfirstlane(ssrc[e]);
    float2 v0 = *reinterpret_cast<const float2*>(x + (size_t)s0 * DIM + c0);
    ax += v0.x;
    ay += v0.y;
  }
  int deg = end - beg;
  float inv = 1.0f / (float)(deg > 0 ? deg : 1);
  *reinterpret_cast<float2*>(mean + (size_t)node * DIM + c0) =
      make_float2(ax * inv, ay * inv);
}

// ---------------- W pre-convert: fp32 [K][128] -> fragment-order bf16 hi/lo ----
// Wfrag elem index: ((mat*4 + kt)*2 + part)*4096 + (k8*128 + col)*8 + j
// where k = kt*32 + k8*8 + j  (consistent with GEMM frag reads: k8 = lane>>4).

__global__ void k_wprep(const float* __restrict__ W_in,
                        const float* __restrict__ W_self,
                        const float* __restrict__ W_neigh,
                        unsigned short* __restrict__ Wfrag) {
  int bid = blockIdx.x;          // 0 .. 7*128-1
  int mat = bid >> 7;
  int k = bid & 127;
  int col = threadIdx.x;         // 0..127
  float v = 0.f;
  if (mat == 0) {
    if (k < KIN) v = W_in[(size_t)k * DIM + col];
  } else if (mat <= 3) {
    v = W_self[(size_t)(mat - 1) * DIM * DIM + (size_t)k * DIM + col];
  } else {
    v = W_neigh[(size_t)(mat - 4) * DIM * DIM + (size_t)k * DIM + col];
  }
  unsigned short hb = f2bf(v);
  unsigned short lb = f2bf(v - bf2f(hb));
  int kt = k >> 5, k8 = (k >> 3) & 3, j = k & 7;
  size_t base = ((size_t)(mat * 4 + kt) * 2) * 4096 + ((size_t)k8 * 128 + col) * 8 + j;
  Wfrag[base] = hb;            // hi block (part 0)
  Wfrag[base + 4096] = lb;     // lo block (part 1)
}

// ---------------- MFMA GEMM: out = act(A@W [+ A2@W2] + bias) ----------------
// 3-term bf16 split (hi*hi + hi*lo + lo*hi) for fp32-class accuracy.
// Tile 128x128, K=128 (4 k-tiles of 32), 4 waves of 64x64, 16x16x32 MFMA.
// A fp32 row-major (split during staging); W pre-converted fragment-order.
// LDS conflict audit (16-lane beats, 16B/lane): A-stage writes = 2-way (free),
// B-stage writes = 2-way (free), fragment reads 256B-contiguous = 2-way (free).

template <int ACT, bool TWO>
__global__ __launch_bounds__(256) void k_gemm_mfma(
    const float* __restrict__ A, int lda, int Kvalid,
    const unsigned short* __restrict__ Wf0,
    const float* __restrict__ A2,
    const unsigned short* __restrict__ Wf1,
    const float* __restrict__ bias,
    float* __restrict__ out, int M) {
  __shared__ s16x8 Ah[512], Al[512], Bh[512], Bl[512];  // [k8*128 + row/col]
  const int tid = threadIdx.x;
  const int lane = tid & 63;
  const int w = tid >> 6;
  const int wr = (w >> 1) * 64, wc = (w & 1) * 64;
  const int l15 = lane & 15, l4 = lane >> 4;
  const int m0 = blockIdx.x * 128;

  f32x4 acc[4][4];
#pragma unroll
  for (int r = 0; r < 4; ++r)
#pragma unroll
    for (int c = 0; c < 4; ++c) acc[r][c] = (f32x4){0.f, 0.f, 0.f, 0.f};

  const int srow = tid >> 1;     // staging row 0..127
  const int shalf = tid & 1;     // staging k-half

  for (int pass = 0; pass < (TWO ? 2 : 1); ++pass) {
    const float* Ap = pass ? A2 : A;
    const unsigned short* Wp = pass ? Wf1 : Wf0;
    const int ld = pass ? DIM : lda;
    const int Kv = pass ? DIM : Kvalid;
    for (int kt = 0; kt < 4; ++kt) {
      __syncthreads();  // previous iteration's reads done before overwrite
      // ---- stage A: read 16 fp32, split to hi/lo bf16, 2 slots ----
      {
        int kbase = kt * 32 + shalf * 16;
        float xv[16];
        const int row = m0 + srow;
        if (row < M && (ld & 3) == 0 && kbase + 16 <= Kv) {
          const float* sp = Ap + (size_t)row * ld + kbase;
#pragma unroll
          for (int q = 0; q < 4; ++q) {
            float4 v = *reinterpret_cast<const float4*>(sp + q * 4);
            xv[q * 4 + 0] = v.x; xv[q * 4 + 1] = v.y;
            xv[q * 4 + 2] = v.z; xv[q * 4 + 3] = v.w;
          }
        } else {
#pragma unroll
          for (int i = 0; i < 16; ++i) {
            int k = kbase + i;
            xv[i] = (row < M && k < Kv) ? Ap[(size_t)row * ld + k] : 0.f;
          }
        }
#pragma unroll
        for (int q = 0; q < 2; ++q) {
          s16x8 hv, lv;
#pragma unroll
          for (int j = 0; j < 8; ++j) {
            float xf = xv[q * 8 + j];
            unsigned short hb = f2bf(xf);
            unsigned short lb = f2bf(xf - bf2f(hb));
            hv[j] = (short)hb;
            lv[j] = (short)lb;
          }
          int slot = (2 * shalf + q) * 128 + srow;
          Ah[slot] = hv;
          Al[slot] = lv;
        }
      }
      // ---- stage W: verbatim coalesced copy of fragment-order block ----
      {
        const s16x8* gW = reinterpret_cast<const s16x8*>(Wp + (size_t)kt * 8192);
#pragma unroll
        for (int r = 0; r < 2; ++r) {
          int s = r * 256 + tid;       // 0..511
          Bh[s] = gW[s];
          Bl[s] = gW[512 + s];
        }
      }
      __syncthreads();
      // ---- fragments + MFMA ----
      s16x8 ah[4], al_[4], bh[4], bl[4];
#pragma unroll
      for (int r = 0; r < 4; ++r) {
        int off = l4 * 128 + wr + r * 16 + l15;
        ah[r] = Ah[off];
        al_[r] = Al[off];
      }
#pragma unroll
      for (int c = 0; c < 4; ++c) {
        int off = l4 * 128 + wc + c * 16 + l15;
        bh[c] = Bh[off];
        bl[c] = Bl[off];
      }
#pragma unroll
      for (int r = 0; r < 4; ++r)
#pragma unroll
        for (int c = 0; c < 4; ++c) {
          acc[r][c] = __builtin_amdgcn_mfma_f32_16x16x32_bf16(
              __builtin_bit_cast(bf16x8, ah[r]), __builtin_bit_cast(bf16x8, bh[c]),
              acc[r][c], 0, 0, 0);
          acc[r][c] = __builtin_amdgcn_mfma_f32_16x16x32_bf16(
              __builtin_bit_cast(bf16x8, ah[r]), __builtin_bit_cast(bf16x8, bl[c]),
              acc[r][c], 0, 0, 0);
          acc[r][c] = __builtin_amdgcn_mfma_f32_16x16x32_bf16(
              __builtin_bit_cast(bf16x8, al_[r]), __builtin_bit_cast(bf16x8, bh[c]),
              acc[r][c], 0, 0, 0);
        }
    }
  }

  // ---- epilogue: bias + act + fp32 store ----
  // D layout (m89): col = lane&15, row = 4*(lane>>4) + reg
#pragma unroll
  for (int c = 0; c < 4; ++c) {
    int col = wc + c * 16 + l15;
    float bv = bias[col];
#pragma unroll
    for (int r = 0; r < 4; ++r) {
#pragma unroll
      for (int i = 0; i < 4; ++i) {
        int row = m0 + wr + r * 16 + l4 * 4 + i;
        if (row < M) {
          float v = acc[r][c][i] + bv;
          if (ACT == 0) v = tanhf(v);
          else v = fmaxf(v, 0.f);
          out[(size_t)row * DIM + col] = v;
        }
      }
    }
  }
}

// ---------------- launcher ----------------

extern "C" void kernel_launch(void* const* d_in, const int* in_sizes, int n_in,
                              void* d_out, int out_size, void* d_ws, size_t ws_size,
                              hipStream_t stream) {
  const float* h0 = (const float*)d_in[0];
  const int* srcp = (const int*)d_in[1];
  const int* dstp = (const int*)d_in[2];
  const float* W_in = (const float*)d_in[3];
  const float* b_in = (const float*)d_in[4];
  const float* W_self = (const float*)d_in[5];
  const float* W_neigh = (const float*)d_in[6];
  const float* b_sage = (const float*)d_in[7];
  float* outf = (float*)d_out;

  char* p = (char*)d_ws;
  auto alloc = [&](size_t bytes) {
    char* r = p;
    p += (bytes + 255) & ~(size_t)255;
    return r;
  };
  float* mean = (float*)alloc((size_t)NN * DIM * 4);
  float* hA = (float*)alloc((size_t)NN * DIM * 4);
  int* cnt = (int*)alloc((size_t)NN * 4);
  int* part = (int*)alloc((size_t)NN * 4);
  int* rptr = (int*)alloc((size_t)(NN + 1) * 4);
  int* cursor = (int*)alloc((size_t)NN * 4);
  int* ssrcS = (int*)alloc((size_t)NE * 4);
  int* bsum = (int*)alloc((size_t)NB * 4);
  int* boff = (int*)alloc((size_t)NB * 4);
  unsigned short* Wfrag = (unsigned short*)alloc((size_t)NMAT * 4 * 2 * 4096 * 2);

  // ---- W pre-convert (fragment-order bf16 hi/lo) ----
  k_wprep<<<NMAT * 128, 128, 0, stream>>>(W_in, W_self, W_neigh, Wfrag);

  // ---- CSR build ----
  hipMemsetAsync(cnt, 0, (size_t)NN * 4, stream);
  k_hist<<<(NE + 255) / 256, 256, 0, stream>>>(dstp, cnt);
  k_scanA<<<NB, 1024, 0, stream>>>(cnt, part, bsum);
  k_scanB<<<1, 64, 0, stream>>>(bsum, boff, rptr);
  k_scanC<<<NB, 1024, 0, stream>>>(part, boff, rptr, cursor);
  k_scatter<<<(NE + 255) / 256, 256, 0, stream>>>(srcp, dstp, cursor, ssrcS);

  const int GB = (NN + 127) / 128;  // 782 blocks
  auto wmat = [&](int mat) { return Wfrag + (size_t)mat * 32768; };

  // ---- f_in: hA = tanh(h0 @ W_in + b_in) ----
  k_gemm_mfma<0, false><<<GB, 256, 0, stream>>>(h0, KIN, KIN, wmat(0), nullptr,
                                                nullptr, b_in, hA, NN);

  // ---- 3 SAGE layers, ping-pong hA <-> d_out ----
  for (int l = 0; l < NLAYERS; ++l) {
    const float* x = (l == 1) ? outf : hA;
    float* o = (l == 1) ? hA : outf;
    const float* bs = b_sage + (size_t)l * DIM;
    k_agg<<<(NN * 64 + 255) / 256, 256, 0, stream>>>(x, rptr, ssrcS, mean);
    k_gemm_mfma<1, true><<<GB, 256, 0, stream>>>(x, DIM, DIM, wmat(1 + l), mean,
                                                 wmat(4 + l), bs, o, NN);
  }
}

// Round 14
// 821.058 us; speedup vs baseline: 1.2462x; 1.0294x over previous
//
#include <hip/hip_runtime.h>
#include <hip/hip_bf16.h>
#include <cstdint>
#include <cstddef>

#define NN 100000
#define NE 1600000
#define DIM 128
#define KIN 117
#define NLAYERS 3
#define NB 98           // ceil(NN/1024)
#define NMAT 7          // W_in + 3x W_self + 3x W_neigh
#define NBUCK 782       // ceil(NN/128) coarse dst-buckets
#define CH 8192         // edges per k_part1 block
#define P1B 196         // ceil(NE/CH)

typedef __attribute__((ext_vector_type(8))) short s16x8;
typedef __attribute__((ext_vector_type(8))) __bf16 bf16x8;
typedef __attribute__((ext_vector_type(4))) float f32x4;

// float -> bf16 bits, round-to-nearest-even (values are finite)
__device__ __forceinline__ unsigned short f2bf(float f) {
  unsigned int u = __float_as_uint(f);
  unsigned int r = (u + 0x7fffu + ((u >> 16) & 1u)) >> 16;
  return (unsigned short)r;
}
__device__ __forceinline__ float bf2f(unsigned short b) {
  return __uint_as_float(((unsigned int)b) << 16);
}

// ---------------- CSR build ----------------

__global__ void k_hist(const int* __restrict__ dst, int* __restrict__ cnt) {
  int i = blockIdx.x * blockDim.x + threadIdx.x;
  if (i < NE) atomicAdd(&cnt[dst[i]], 1);
}

__global__ void k_scanA(const int* __restrict__ cnt, int* __restrict__ part,
                        int* __restrict__ bsum) {
  __shared__ int sh[1024];
  int tid = threadIdx.x;
  int i = blockIdx.x * 1024 + tid;
  int v = (i < NN) ? cnt[i] : 0;
  sh[tid] = v;
  __syncthreads();
  for (int off = 1; off < 1024; off <<= 1) {
    int t = (tid >= off) ? sh[tid - off] : 0;
    __syncthreads();
    sh[tid] += t;
    __syncthreads();
  }
  if (i < NN) part[i] = sh[tid] - v;   // exclusive within block
  if (tid == 1023) bsum[blockIdx.x] = sh[1023];
}

__global__ void k_scanB(const int* __restrict__ bsum, int* __restrict__ boff,
                        int* __restrict__ rptr) {
  if (threadIdx.x == 0 && blockIdx.x == 0) {
    int run = 0;
    for (int b = 0; b < NB; ++b) { boff[b] = run; run += bsum[b]; }
    rptr[NN] = run;  // == NE
  }
}

__global__ void k_scanC(const int* __restrict__ part, const int* __restrict__ boff,
                        int* __restrict__ rptr) {
  int i = blockIdx.x * 1024 + threadIdx.x;
  if (i < NN) rptr[i] = part[i] + boff[i >> 10];
}

// gcur[b] = rptr[b*128]  (per-call re-init; k_part1 mutates it)
__global__ void k_initg(const int* __restrict__ rptr, int* __restrict__ gcur) {
  int t = blockIdx.x * blockDim.x + threadIdx.x;
  if (t < NBUCK) gcur[t] = rptr[t << 7];
}

// ---- pass 1: partition edges into 782 coarse buckets (dst>>7) ----
// Per block: LDS counting sort of an 8192-edge chunk, then contiguous
// run writes into globally reserved ranges. payload = src | (dst&127)<<17.
__global__ __launch_bounds__(256) void k_part1(const int* __restrict__ src,
                                               const int* __restrict__ dst,
                                               int* __restrict__ gcur,
                                               int* __restrict__ epart) {
  __shared__ int hist[NBUCK];
  __shared__ int lofs[NBUCK + 1];
  __shared__ int cur[NBUCK];
  __shared__ int base[NBUCK];
  __shared__ int sorted[CH];
  __shared__ int psum[256];
  const int tid = threadIdx.x;
  const int e0 = blockIdx.x * CH;
  const int n = (NE - e0 < CH) ? (NE - e0) : CH;

  for (int b = tid; b < NBUCK; b += 256) { hist[b] = 0; cur[b] = 0; }
  __syncthreads();
  for (int j = tid; j < n; j += 256)
    atomicAdd(&hist[dst[e0 + j] >> 7], 1);
  __syncthreads();
  // blocked exclusive scan of hist -> lofs (thread t owns elems 4t..4t+3)
  {
    int b0 = tid * 4;
    int loc[4];
    int s = 0;
    for (int q = 0; q < 4; ++q) {
      int b = b0 + q;
      loc[q] = s;
      if (b < NBUCK) s += hist[b];
    }
    psum[tid] = s;
    __syncthreads();
    for (int off = 1; off < 256; off <<= 1) {
      int t = (tid >= off) ? psum[tid - off] : 0;
      __syncthreads();
      psum[tid] += t;
      __syncthreads();
    }
    int excl = (tid == 0) ? 0 : psum[tid - 1];
    for (int q = 0; q < 4; ++q) {
      int b = b0 + q;
      if (b < NBUCK) lofs[b] = excl + loc[q];
    }
    if (tid == 0) lofs[NBUCK] = n;
  }
  __syncthreads();
  // local scatter into sorted[]
  for (int j = tid; j < n; j += 256) {
    int d = dst[e0 + j];
    int b = d >> 7;
    int pos = atomicAdd(&cur[b], 1);
    sorted[lofs[b] + pos] = (src[e0 + j] & 0x1FFFF) | ((d & 127) << 17);
  }
  // reserve global ranges
  for (int b = tid; b < NBUCK; b += 256) {
    int h = hist[b];
    if (h) base[b] = atomicAdd(&gcur[b], h);
  }
  __syncthreads();
  // write out; bucket of j via binary search in lofs
  for (int j = tid; j < n; j += 256) {
    int lo = 0, hi = NBUCK;
    while (hi - lo > 1) {
      int mid = (lo + hi) >> 1;
      if (lofs[mid] <= j) lo = mid; else hi = mid;
    }
    epart[base[lo] + (j - lofs[lo])] = sorted[j];
  }
}

// ---- pass 2: within-bucket counting scatter -> final dst-sorted ssrc ----
// Block b exclusively owns output range [rptr[b*128], rptr[min((b+1)*128,NN)]).
__global__ __launch_bounds__(256) void k_part2(const int* __restrict__ epart,
                                               const int* __restrict__ rptr,
                                               int* __restrict__ ssrc) {
  __shared__ int curs[128];
  const int b = blockIdx.x;
  const int tid = threadIdx.x;
  const int nb0 = b << 7;
  if (tid < 128) {
    int idx = nb0 + tid;
    curs[tid] = (idx < NN) ? rptr[idx] : NE;
  }
  const int lo = rptr[nb0];
  const int hi_idx = (nb0 + 128 < NN) ? (nb0 + 128) : NN;
  const int hi = rptr[hi_idx];
  __syncthreads();
  for (int j = lo + tid; j < hi; j += 256) {
    int w = epart[j];
    int p = atomicAdd(&curs[(w >> 17) & 127], 1);
    ssrc[p] = w & 0x1FFFF;
  }
}

// ---------------- mean aggregation: one wave per node ----------------

__global__ __launch_bounds__(256) void k_agg(const float* __restrict__ x,
                                             const int* __restrict__ rptr,
                                             const int* __restrict__ ssrc,
                                             float* __restrict__ mean) {
  int gid = blockIdx.x * blockDim.x + threadIdx.x;
  int node = __builtin_amdgcn_readfirstlane(gid >> 6);
  int lane = threadIdx.x & 63;
  if (node >= NN) return;
  int beg = __builtin_amdgcn_readfirstlane(rptr[node]);
  int end = __builtin_amdgcn_readfirstlane(rptr[node + 1]);
  int c0 = lane * 2;
  float ax = 0.f, ay = 0.f;
  int e = beg;
  for (; e + 3 < end; e += 4) {
    int s0 = __builtin_amdgcn_readfirstlane(ssrc[e]);
    int s1 = __builtin_amdgcn_readfirstlane(ssrc[e + 1]);
    int s2 = __builtin_amdgcn_readfirstlane(ssrc[e + 2]);
    int s3 = __builtin_amdgcn_readfirstlane(ssrc[e + 3]);
    float2 v0 = *reinterpret_cast<const float2*>(x + (size_t)s0 * DIM + c0);
    float2 v1 = *reinterpret_cast<const float2*>(x + (size_t)s1 * DIM + c0);
    float2 v2 = *reinterpret_cast<const float2*>(x + (size_t)s2 * DIM + c0);
    float2 v3 = *reinterpret_cast<const float2*>(x + (size_t)s3 * DIM + c0);
    ax += (v0.x + v1.x) + (v2.x + v3.x);
    ay += (v0.y + v1.y) + (v2.y + v3.y);
  }
  for (; e < end; ++e) {
    int s0 = __builtin_amdgcn_readfirstlane(ssrc[e]);
    float2 v0 = *reinterpret_cast<const float2*>(x + (size_t)s0 * DIM + c0);
    ax += v0.x;
    ay += v0.y;
  }
  int deg = end - beg;
  float inv = 1.0f / (float)(deg > 0 ? deg : 1);
  *reinterpret_cast<float2*>(mean + (size_t)node * DIM + c0) =
      make_float2(ax * inv, ay * inv);
}

// ---------------- W pre-convert: fp32 [K][128] -> fragment-order bf16 hi/lo ----
// Wfrag elem index: ((mat*4 + kt)*2 + part)*4096 + (k8*128 + col)*8 + j
// where k = kt*32 + k8*8 + j  (consistent with GEMM frag reads: k8 = lane>>4).

__global__ void k_wprep(const float* __restrict__ W_in,
                        const float* __restrict__ W_self,
                        const float* __restrict__ W_neigh,
                        unsigned short* __restrict__ Wfrag) {
  int bid = blockIdx.x;          // 0 .. 7*128-1
  int mat = bid >> 7;
  int k = bid & 127;
  int col = threadIdx.x;         // 0..127
  float v = 0.f;
  if (mat == 0) {
    if (k < KIN) v = W_in[(size_t)k * DIM + col];
  } else if (mat <= 3) {
    v = W_self[(size_t)(mat - 1) * DIM * DIM + (size_t)k * DIM + col];
  } else {
    v = W_neigh[(size_t)(mat - 4) * DIM * DIM + (size_t)k * DIM + col];
  }
  unsigned short hb = f2bf(v);
  unsigned short lb = f2bf(v - bf2f(hb));
  int kt = k >> 5, k8 = (k >> 3) & 3, j = k & 7;
  size_t base = ((size_t)(mat * 4 + kt) * 2) * 4096 + ((size_t)k8 * 128 + col) * 8 + j;
  Wfrag[base] = hb;            // hi block (part 0)
  Wfrag[base + 4096] = lb;     // lo block (part 1)
}

// ---------------- MFMA GEMM: out = act(A@W [+ A2@W2] + bias) ----------------
// 3-term bf16 split (hi*hi + hi*lo + lo*hi) for fp32-class accuracy.
// Tile 128x128, K=128 (4 k-tiles of 32), 4 waves of 64x64, 16x16x32 MFMA.

template <int ACT, bool TWO>
__global__ __launch_bounds__(256) void k_gemm_mfma(
    const float* __restrict__ A, int lda, int Kvalid,
    const unsigned short* __restrict__ Wf0,
    const float* __restrict__ A2,
    const unsigned short* __restrict__ Wf1,
    const float* __restrict__ bias,
    float* __restrict__ out, int M) {
  __shared__ s16x8 Ah[512], Al[512], Bh[512], Bl[512];  // [k8*128 + row/col]
  const int tid = threadIdx.x;
  const int lane = tid & 63;
  const int w = tid >> 6;
  const int wr = (w >> 1) * 64, wc = (w & 1) * 64;
  const int l15 = lane & 15, l4 = lane >> 4;
  const int m0 = blockIdx.x * 128;

  f32x4 acc[4][4];
#pragma unroll
  for (int r = 0; r < 4; ++r)
#pragma unroll
    for (int c = 0; c < 4; ++c) acc[r][c] = (f32x4){0.f, 0.f, 0.f, 0.f};

  const int srow = tid >> 1;     // staging row 0..127
  const int shalf = tid & 1;     // staging k-half

  for (int pass = 0; pass < (TWO ? 2 : 1); ++pass) {
    const float* Ap = pass ? A2 : A;
    const unsigned short* Wp = pass ? Wf1 : Wf0;
    const int ld = pass ? DIM : lda;
    const int Kv = pass ? DIM : Kvalid;
    for (int kt = 0; kt < 4; ++kt) {
      __syncthreads();  // previous iteration's reads done before overwrite
      // ---- stage A: read 16 fp32, split to hi/lo bf16, 2 slots ----
      {
        int kbase = kt * 32 + shalf * 16;
        float xv[16];
        const int row = m0 + srow;
        if (row < M && (ld & 3) == 0 && kbase + 16 <= Kv) {
          const float* sp = Ap + (size_t)row * ld + kbase;
#pragma unroll
          for (int q = 0; q < 4; ++q) {
            float4 v = *reinterpret_cast<const float4*>(sp + q * 4);
            xv[q * 4 + 0] = v.x; xv[q * 4 + 1] = v.y;
            xv[q * 4 + 2] = v.z; xv[q * 4 + 3] = v.w;
          }
        } else {
#pragma unroll
          for (int i = 0; i < 16; ++i) {
            int k = kbase + i;
            xv[i] = (row < M && k < Kv) ? Ap[(size_t)row * ld + k] : 0.f;
          }
        }
#pragma unroll
        for (int q = 0; q < 2; ++q) {
          s16x8 hv, lv;
#pragma unroll
          for (int j = 0; j < 8; ++j) {
            float xf = xv[q * 8 + j];
            unsigned short hb = f2bf(xf);
            unsigned short lb = f2bf(xf - bf2f(hb));
            hv[j] = (short)hb;
            lv[j] = (short)lb;
          }
          int slot = (2 * shalf + q) * 128 + srow;
          Ah[slot] = hv;
          Al[slot] = lv;
        }
      }
      // ---- stage W: verbatim coalesced copy of fragment-order block ----
      {
        const s16x8* gW = reinterpret_cast<const s16x8*>(Wp + (size_t)kt * 8192);
#pragma unroll
        for (int r = 0; r < 2; ++r) {
          int s = r * 256 + tid;       // 0..511
          Bh[s] = gW[s];
          Bl[s] = gW[512 + s];
        }
      }
      __syncthreads();
      // ---- fragments + MFMA ----
      s16x8 ah[4], al_[4], bh[4], bl[4];
#pragma unroll
      for (int r = 0; r < 4; ++r) {
        int off = l4 * 128 + wr + r * 16 + l15;
        ah[r] = Ah[off];
        al_[r] = Al[off];
      }
#pragma unroll
      for (int c = 0; c < 4; ++c) {
        int off = l4 * 128 + wc + c * 16 + l15;
        bh[c] = Bh[off];
        bl[c] = Bl[off];
      }
#pragma unroll
      for (int r = 0; r < 4; ++r)
#pragma unroll
        for (int c = 0; c < 4; ++c) {
          acc[r][c] = __builtin_amdgcn_mfma_f32_16x16x32_bf16(
              __builtin_bit_cast(bf16x8, ah[r]), __builtin_bit_cast(bf16x8, bh[c]),
              acc[r][c], 0, 0, 0);
          acc[r][c] = __builtin_amdgcn_mfma_f32_16x16x32_bf16(
              __builtin_bit_cast(bf16x8, ah[r]), __builtin_bit_cast(bf16x8, bl[c]),
              acc[r][c], 0, 0, 0);
          acc[r][c] = __builtin_amdgcn_mfma_f32_16x16x32_bf16(
              __builtin_bit_cast(bf16x8, al_[r]), __builtin_bit_cast(bf16x8, bh[c]),
              acc[r][c], 0, 0, 0);
        }
    }
  }

  // ---- epilogue: bias + act + fp32 store ----
  // D layout (m89): col = lane&15, row = 4*(lane>>4) + reg
#pragma unroll
  for (int c = 0; c < 4; ++c) {
    int col = wc + c * 16 + l15;
    float bv = bias[col];
#pragma unroll
    for (int r = 0; r < 4; ++r) {
#pragma unroll
      for (int i = 0; i < 4; ++i) {
        int row = m0 + wr + r * 16 + l4 * 4 + i;
        if (row < M) {
          float v = acc[r][c][i] + bv;
          if (ACT == 0) v = tanhf(v);
          else v = fmaxf(v, 0.f);
          out[(size_t)row * DIM + col] = v;
        }
      }
    }
  }
}

// ---------------- launcher ----------------

extern "C" void kernel_launch(void* const* d_in, const int* in_sizes, int n_in,
                              void* d_out, int out_size, void* d_ws, size_t ws_size,
                              hipStream_t stream) {
  const float* h0 = (const float*)d_in[0];
  const int* srcp = (const int*)d_in[1];
  const int* dstp = (const int*)d_in[2];
  const float* W_in = (const float*)d_in[3];
  const float* b_in = (const float*)d_in[4];
  const float* W_self = (const float*)d_in[5];
  const float* W_neigh = (const float*)d_in[6];
  const float* b_sage = (const float*)d_in[7];
  float* outf = (float*)d_out;

  char* p = (char*)d_ws;
  auto alloc = [&](size_t bytes) {
    char* r = p;
    p += (bytes + 255) & ~(size_t)255;
    return r;
  };
  float* mean = (float*)alloc((size_t)NN * DIM * 4);
  float* hA = (float*)alloc((size_t)NN * DIM * 4);
  int* cnt = (int*)alloc((size_t)NN * 4);
  int* part = (int*)alloc((size_t)NN * 4);
  int* rptr = (int*)alloc((size_t)(NN + 1) * 4);
  int* gcur = (int*)alloc((size_t)NBUCK * 4);
  int* ssrcS = (int*)alloc((size_t)NE * 4);
  int* bsum = (int*)alloc((size_t)NB * 4);
  int* boff = (int*)alloc((size_t)NB * 4);
  unsigned short* Wfrag = (unsigned short*)alloc((size_t)NMAT * 4 * 2 * 4096 * 2);
  // epart aliases mean: lifetimes disjoint (partition finishes before first k_agg)
  int* epart = (int*)mean;

  // ---- W pre-convert (fragment-order bf16 hi/lo) ----
  k_wprep<<<NMAT * 128, 128, 0, stream>>>(W_in, W_self, W_neigh, Wfrag);

  // ---- CSR build: hist -> scan -> two-pass single-writer partition ----
  hipMemsetAsync(cnt, 0, (size_t)NN * 4, stream);
  k_hist<<<(NE + 255) / 256, 256, 0, stream>>>(dstp, cnt);
  k_scanA<<<NB, 1024, 0, stream>>>(cnt, part, bsum);
  k_scanB<<<1, 64, 0, stream>>>(bsum, boff, rptr);
  k_scanC<<<NB, 1024, 0, stream>>>(part, boff, rptr);
  k_initg<<<(NBUCK + 255) / 256, 256, 0, stream>>>(rptr, gcur);
  k_part1<<<P1B, 256, 0, stream>>>(srcp, dstp, gcur, epart);
  k_part2<<<NBUCK, 256, 0, stream>>>(epart, rptr, ssrcS);

  const int GB = (NN + 127) / 128;  // 782 blocks
  auto wmat = [&](int mat) { return Wfrag + (size_t)mat * 32768; };

  // ---- f_in: hA = tanh(h0 @ W_in + b_in) ----
  k_gemm_mfma<0, false><<<GB, 256, 0, stream>>>(h0, KIN, KIN, wmat(0), nullptr,
                                                nullptr, b_in, hA, NN);

  // ---- 3 SAGE layers, ping-pong hA <-> d_out ----
  for (int l = 0; l < NLAYERS; ++l) {
    const float* x = (l == 1) ? outf : hA;
    float* o = (l == 1) ? hA : outf;
    const float* bs = b_sage + (size_t)l * DIM;
    k_agg<<<(NN * 64 + 255) / 256, 256, 0, stream>>>(x, rptr, ssrcS, mean);
    k_gemm_mfma<1, true><<<GB, 256, 0, stream>>>(x, DIM, DIM, wmat(1 + l), mean,
                                                 wmat(4 + l), bs, o, NN);
  }
}